// Round 13
// baseline (181.166 us; speedup 1.0000x reference)
//
#include <hip/hip_runtime.h>

#define B_ 512
#define D_ 512
#define L_ 32
#define H_ 300
#define NT 19       // 16-col n-tiles of H
#define NS 10       // 32-k steps over K=300 (zero-padded weights beyond 300)
#define G1S 308     // g1 LDS row stride (ushorts): <=2-way on stores+reads (measured 0)
#define HS 312      // fused-encoder LDS row stride (ushorts), 16B-aligned rows

typedef unsigned short ushort_t;
typedef __bf16 bf16x8 __attribute__((ext_vector_type(8)));
typedef float f32x4 __attribute__((ext_vector_type(4)));

union B8 { ushort_t u[8]; uint4 q; bf16x8 v; uint2 d[2]; __bf16 b[8]; };

__device__ __forceinline__ void split8(const float* fv, B8& hi, B8& lo) {
    #pragma unroll
    for (int i = 0; i < 8; ++i) {
        __bf16 h = (__bf16)fv[i];
        hi.b[i] = h;
        lo.b[i] = (__bf16)(fv[i] - (float)h);
    }
}

// ---------------- prep: swizzle weights into MFMA fragment layout ----------------
// frag elem i of lane l = B[k = 32*s + 8*(l>>4) + i][n = 16*nt + (l&15)]; OOR -> 0
__global__ __launch_bounds__(64) void prep_kernel(
        const float* __restrict__ gw1, const float* __restrict__ gw2,
        const float* __restrict__ qw1, const float* __restrict__ qw2,
        const float* __restrict__ zmw, const float* __restrict__ zlw,
        ushort_t* __restrict__ gw1f, ushort_t* __restrict__ gw2f,
        ushort_t* __restrict__ w1hi, ushort_t* __restrict__ w1lo,
        ushort_t* __restrict__ w2hi, ushort_t* __restrict__ w2lo,
        ushort_t* __restrict__ w3hi, ushort_t* __restrict__ w3lo) {
    int blk = blockIdx.x;
    int l = threadIdx.x, grp = l >> 4, li = l & 15;
    if (blk < 209) {    // decoder weights, single bf16
        const float* src; int K, nt, s; ushort_t* dst;
        if (blk < 19) { nt = blk; s = 0; src = gw1; K = 32; dst = gw1f + (nt * 64 + l) * 8; }
        else { int i = blk - 19; nt = i / 10; s = i % 10; src = gw2; K = 300;
               dst = gw2f + ((nt * 10 + s) * 64 + l) * 8; }
        int n = nt * 16 + li;
        B8 V;
        #pragma unroll
        for (int i = 0; i < 8; ++i) {
            int k = 32 * s + 8 * grp + i;
            V.b[i] = (__bf16)((k < K && n < H_) ? src[k * H_ + n] : 0.f);
        }
        *reinterpret_cast<uint4*>(dst) = V.q;
    } else {            // encoder weights, hi/lo split
        const float* src = nullptr; int K, N, nt, s, stacked = 0;
        ushort_t *dh, *dl;
        if (blk < 513)      { int i = blk - 209; nt = i / 16; s = i % 16; src = qw1; K = 512; N = 300;
                              dh = w1hi + ((nt * 16 + s) * 64 + l) * 8; dl = w1lo + ((nt * 16 + s) * 64 + l) * 8; }
        else if (blk < 703) { int i = blk - 513; nt = i / 10; s = i % 10; src = qw2; K = 300; N = 300;
                              dh = w2hi + ((nt * 10 + s) * 64 + l) * 8; dl = w2lo + ((nt * 10 + s) * 64 + l) * 8; }
        else                { int i = blk - 703; nt = i / 10; s = i % 10; K = 300; N = 64; stacked = 1;
                              dh = w3hi + ((nt * 10 + s) * 64 + l) * 8; dl = w3lo + ((nt * 10 + s) * 64 + l) * 8; }
        int n = nt * 16 + li;
        float fv[8];
        #pragma unroll
        for (int i = 0; i < 8; ++i) {
            int k = 32 * s + 8 * grp + i;
            float v = 0.f;
            if (k < K && n < N) {
                if (!stacked) v = src[k * N + n];
                else          v = (n < 32) ? zmw[k * 32 + n] : zlw[k * 32 + (n - 32)];
            }
            fv[i] = v;
        }
        B8 Vh, Vl;
        split8(fv, Vh, Vl);
        *reinterpret_cast<uint4*>(dh) = Vh.q;
        *reinterpret_cast<uint4*>(dl) = Vl.q;
    }
}

// ---------- fused encoder: x -> h1 -> h2 -> (zm|zl) -> z; 32 blocks x 512 thr ----------
// Block = 16 batch rows, 8 waves. Stages 1-2: 19 n-tiles = 3+3+3+2+2+2+2+2 across waves.
__global__ __launch_bounds__(512) void fused_encoder(
        const float* __restrict__ x,
        const ushort_t* __restrict__ w1hi, const ushort_t* __restrict__ w1lo,
        const ushort_t* __restrict__ w2hi, const ushort_t* __restrict__ w2lo,
        const ushort_t* __restrict__ w3hi, const ushort_t* __restrict__ w3lo,
        const float* __restrict__ b1, const float* __restrict__ b2,
        const float* __restrict__ zmb, const float* __restrict__ zlb,
        const float* __restrict__ eps, float* __restrict__ out,
        float* __restrict__ zb) {
    __shared__ __align__(16) ushort_t hs1_hi[16 * HS + 16], hs1_lo[16 * HS + 16];
    __shared__ __align__(16) ushort_t hs2_hi[16 * HS + 16], hs2_lo[16 * HS + 16];
    __shared__ float zs2[64][17];

    const int tid = threadIdx.x;
    const int w = tid >> 6, lane = tid & 63;
    const int grp = lane >> 4, li = lane & 15;
    const int r0 = blockIdx.x * 16;
    const int nlocal = (w < 3) ? 3 : 2;
    const int nbeg   = (w < 3) ? w * 3 : 9 + (w - 3) * 2;

    for (int idx = tid; idx < 16 * 8 + 16; idx += 512) {
        int off = (idx < 128) ? ((idx >> 3) * HS + 304 + (idx & 7)) : (16 * HS + (idx - 128));
        hs1_hi[off] = 0; hs1_lo[off] = 0; hs2_hi[off] = 0; hs2_lo[off] = 0;
    }
    __syncthreads();

    // ---- stage 1: h1 = relu(x @ W1 + b1), K=512 (16 s-steps) ----
    {
        f32x4 acc[3];
        #pragma unroll
        for (int i = 0; i < 3; ++i) acc[i] = {0.f, 0.f, 0.f, 0.f};
        for (int s = 0; s < 16; ++s) {
            const float* ap = x + (size_t)(r0 + li) * 512 + 32 * s + 8 * grp;
            float4 f0 = *reinterpret_cast<const float4*>(ap);
            float4 f1 = *reinterpret_cast<const float4*>(ap + 4);
            float fv[8] = {f0.x, f0.y, f0.z, f0.w, f1.x, f1.y, f1.z, f1.w};
            B8 Bh, Bl;
            split8(fv, Bh, Bl);
            #pragma unroll
            for (int ntl = 0; ntl < 3; ++ntl) {
                if (ntl < nlocal) {
                    int nt = nbeg + ntl;
                    bf16x8 Ah = *reinterpret_cast<const bf16x8*>(
                        w1hi + ((size_t)(nt * 16 + s) * 64 + lane) * 8);
                    bf16x8 Al = *reinterpret_cast<const bf16x8*>(
                        w1lo + ((size_t)(nt * 16 + s) * 64 + lane) * 8);
                    acc[ntl] = __builtin_amdgcn_mfma_f32_16x16x32_bf16(Ah, Bh.v, acc[ntl], 0, 0, 0);
                    acc[ntl] = __builtin_amdgcn_mfma_f32_16x16x32_bf16(Al, Bh.v, acc[ntl], 0, 0, 0);
                    acc[ntl] = __builtin_amdgcn_mfma_f32_16x16x32_bf16(Ah, Bl.v, acc[ntl], 0, 0, 0);
                }
            }
        }
        #pragma unroll
        for (int ntl = 0; ntl < 3; ++ntl) {
            if (ntl < nlocal) {
                int nt = nbeg + ntl;
                B8 Ph, Pl;
                #pragma unroll
                for (int r = 0; r < 4; ++r) {
                    int h = nt * 16 + 4 * grp + r;
                    float v = (h < H_) ? fmaxf(acc[ntl][r] + b1[h], 0.f) : 0.f;
                    __bf16 hb = (__bf16)v;
                    Ph.b[r] = hb;
                    Pl.b[r] = (__bf16)(v - (float)hb);
                }
                int off = li * HS + nt * 16 + 4 * grp;
                *reinterpret_cast<uint2*>(&hs1_hi[off]) = Ph.d[0];
                *reinterpret_cast<uint2*>(&hs1_lo[off]) = Pl.d[0];
            }
        }
    }
    __syncthreads();

    // ---- stage 2: h2 = relu(h1 @ W2 + b2), K=300 (10 s-steps) ----
    {
        f32x4 acc[3];
        #pragma unroll
        for (int i = 0; i < 3; ++i) acc[i] = {0.f, 0.f, 0.f, 0.f};
        for (int s = 0; s < NS; ++s) {
            int off = li * HS + 32 * s + 8 * grp;
            B8 Bh, Bl;
            Bh.q = *reinterpret_cast<const uint4*>(&hs1_hi[off]);
            Bl.q = *reinterpret_cast<const uint4*>(&hs1_lo[off]);
            #pragma unroll
            for (int ntl = 0; ntl < 3; ++ntl) {
                if (ntl < nlocal) {
                    int nt = nbeg + ntl;
                    bf16x8 Ah = *reinterpret_cast<const bf16x8*>(
                        w2hi + ((size_t)(nt * 10 + s) * 64 + lane) * 8);
                    bf16x8 Al = *reinterpret_cast<const bf16x8*>(
                        w2lo + ((size_t)(nt * 10 + s) * 64 + lane) * 8);
                    acc[ntl] = __builtin_amdgcn_mfma_f32_16x16x32_bf16(Ah, Bh.v, acc[ntl], 0, 0, 0);
                    acc[ntl] = __builtin_amdgcn_mfma_f32_16x16x32_bf16(Al, Bh.v, acc[ntl], 0, 0, 0);
                    acc[ntl] = __builtin_amdgcn_mfma_f32_16x16x32_bf16(Ah, Bl.v, acc[ntl], 0, 0, 0);
                }
            }
        }
        #pragma unroll
        for (int ntl = 0; ntl < 3; ++ntl) {
            if (ntl < nlocal) {
                int nt = nbeg + ntl;
                B8 Ph, Pl;
                #pragma unroll
                for (int r = 0; r < 4; ++r) {
                    int h = nt * 16 + 4 * grp + r;
                    float v = (h < H_) ? fmaxf(acc[ntl][r] + b2[h], 0.f) : 0.f;
                    __bf16 hb = (__bf16)v;
                    Ph.b[r] = hb;
                    Pl.b[r] = (__bf16)(v - (float)hb);
                }
                int off = li * HS + nt * 16 + 4 * grp;
                *reinterpret_cast<uint2*>(&hs2_hi[off]) = Ph.d[0];
                *reinterpret_cast<uint2*>(&hs2_lo[off]) = Pl.d[0];
            }
        }
    }
    __syncthreads();

    // ---- stage 3: zm|zl = h2 @ w3 (N=64, waves 0..3 own nt=w) ----
    if (w < 4) {
        f32x4 acc = {0.f, 0.f, 0.f, 0.f};
        for (int s = 0; s < NS; ++s) {
            int off = li * HS + 32 * s + 8 * grp;
            B8 Bh, Bl;
            Bh.q = *reinterpret_cast<const uint4*>(&hs2_hi[off]);
            Bl.q = *reinterpret_cast<const uint4*>(&hs2_lo[off]);
            bf16x8 Ah = *reinterpret_cast<const bf16x8*>(
                w3hi + ((size_t)(w * 10 + s) * 64 + lane) * 8);
            bf16x8 Al = *reinterpret_cast<const bf16x8*>(
                w3lo + ((size_t)(w * 10 + s) * 64 + lane) * 8);
            acc = __builtin_amdgcn_mfma_f32_16x16x32_bf16(Ah, Bh.v, acc, 0, 0, 0);
            acc = __builtin_amdgcn_mfma_f32_16x16x32_bf16(Al, Bh.v, acc, 0, 0, 0);
            acc = __builtin_amdgcn_mfma_f32_16x16x32_bf16(Ah, Bl.v, acc, 0, 0, 0);
        }
        #pragma unroll
        for (int r = 0; r < 4; ++r) zs2[w * 16 + 4 * grp + r][li] = acc[r];
    }
    __syncthreads();

    // ---- reparameterize + write z, z_mean, z_log_var (512 threads = 512 elems) ----
    {
        int m = tid >> 5, l2 = tid & 31;
        int row = r0 + m;
        float zm = zs2[l2][m] + zmb[l2];
        float zl = zs2[32 + l2][m] + zlb[l2];
        float zv = zm + eps[row * 32 + l2] * expf(0.5f * zl);
        out[B_ * D_ + row * 32 + l2] = zv;
        out[B_ * D_ + B_ * L_ + row * 32 + l2] = zm;
        out[B_ * D_ + 2 * B_ * L_ + row * 32 + l2] = zl;
        zb[row * 32 + l2] = zv;
    }
}

// ---------------- decoder: R12 structure + R2-proven B-frag ping-pong prefetch ----------
__global__ __launch_bounds__(256, 3) void decode_kernel(
        const float* __restrict__ z, const float* __restrict__ Wmask,
        const ushort_t* __restrict__ gw1f, const ushort_t* __restrict__ gw2f,
        const float* __restrict__ gb2, const float* __restrict__ colw,
        const float* __restrict__ colb, float* __restrict__ xmean) {
    __shared__ __align__(16) ushort_t g1s[64 * G1S + 16];    // 39,456 B
    __shared__ float xpart[4][64];                           //  1,024 B

    const int j    = blockIdx.y;
    const int b0   = blockIdx.x * 64;
    const int tid  = threadIdx.x;
    const int w    = tid >> 6;
    const int lane = tid & 63;
    const int grp  = lane >> 4, li = lane & 15;
    const int nlocal = (w == 3) ? 4 : 5;          // n-tiles 19 = 5+5+5+4 across waves
    const size_t lane8 = (size_t)lane * 8;

    // prefetch first B-frags early: L2 latency hides under phases 0-1
    bf16x8 bc[5], bn[5];
    #pragma unroll
    for (int ntl = 0; ntl < 5; ++ntl)
        if (ntl < nlocal)
            bc[ntl] = *reinterpret_cast<const bf16x8*>(
                gw2f + (size_t)((w * 5 + ntl) * NS) * 512 + lane8);

    // phase 0: masked B-frags in registers (all 4 m-tiles, per wave); zero pads
    B8 bm[4];
    {
        const float* wp = Wmask + (size_t)j * L_ + 8 * grp;
        float4 w0 = *reinterpret_cast<const float4*>(wp);
        float4 w1 = *reinterpret_cast<const float4*>(wp + 4);
        float wv[8] = {w0.x, w0.y, w0.z, w0.w, w1.x, w1.y, w1.z, w1.w};
        #pragma unroll
        for (int mt = 0; mt < 4; ++mt) {
            const float* zp = z + (size_t)(b0 + mt * 16 + li) * L_ + 8 * grp;
            float4 z0 = *reinterpret_cast<const float4*>(zp);
            float4 z1 = *reinterpret_cast<const float4*>(zp + 4);
            float zv[8] = {z0.x, z0.y, z0.z, z0.w, z1.x, z1.y, z1.z, z1.w};
            #pragma unroll
            for (int i = 0; i < 8; ++i) bm[mt].b[i] = (__bf16)(wv[i] * zv[i]);
        }
        for (int idx = tid; idx < 272; idx += 256) {
            if (idx < 256) g1s[(idx >> 2) * G1S + 304 + (idx & 3)] = 0;
            else           g1s[64 * G1S + (idx - 256)] = 0;
        }
    }
    __syncthreads();

    // phase 1 (swapped): D = gw1^T(A) x masked^T(B) -> lane holds g1[b=li][4 consec h]
    {
        ushort_t* st = &g1s[li * G1S + 4 * grp];
        #pragma unroll
        for (int ntl = 0; ntl < 5; ++ntl) {
            if (ntl < nlocal) {
                int nt = w * 5 + ntl;
                bf16x8 ga = *reinterpret_cast<const bf16x8*>(gw1f + (nt * 64 + lane) * 8);
                #pragma unroll
                for (int mt = 0; mt < 4; ++mt) {
                    f32x4 c = {0.f, 0.f, 0.f, 0.f};
                    c = __builtin_amdgcn_mfma_f32_16x16x32_bf16(ga, bm[mt].v, c, 0, 0, 0);
                    B8 P;
                    #pragma unroll
                    for (int r = 0; r < 4; ++r) P.b[r] = (__bf16)fmaxf(c[r], 0.f);
                    *reinterpret_cast<uint2*>(st + mt * 16 * G1S + nt * 16) = P.d[0];
                }
            }
        }
    }
    __syncthreads();

    // phase 2: g2 = relu(g1 @ gw2 + gb2); ping-pong B prefetch, af reused 5x
    float partial[4][4] = {};
    {
        f32x4 acc[4][5];
        #pragma unroll
        for (int mt = 0; mt < 4; ++mt)
            #pragma unroll
            for (int n = 0; n < 5; ++n) acc[mt][n] = {0.f, 0.f, 0.f, 0.f};

        for (int s = 0; s < NS; s += 2) {
            // prefetch s+1 (NS even -> always valid)
            #pragma unroll
            for (int ntl = 0; ntl < 5; ++ntl)
                if (ntl < nlocal)
                    bn[ntl] = *reinterpret_cast<const bf16x8*>(
                        gw2f + (size_t)((w * 5 + ntl) * NS + s + 1) * 512 + lane8);
            {
                B8 af[4];
                #pragma unroll
                for (int mt = 0; mt < 4; ++mt) {
                    const ushort_t* p = &g1s[(mt * 16 + li) * G1S + 32 * s + 8 * grp];
                    af[mt].d[0] = *reinterpret_cast<const uint2*>(p);
                    af[mt].d[1] = *reinterpret_cast<const uint2*>(p + 4);
                }
                #pragma unroll
                for (int ntl = 0; ntl < 5; ++ntl)
                    if (ntl < nlocal)
                        #pragma unroll
                        for (int mt = 0; mt < 4; ++mt)
                            acc[mt][ntl] = __builtin_amdgcn_mfma_f32_16x16x32_bf16(
                                af[mt].v, bc[ntl], acc[mt][ntl], 0, 0, 0);
            }
            // prefetch s+2 (clamped on last iter; value unused)
            int s2 = (s + 2 < NS) ? (s + 2) : 0;
            #pragma unroll
            for (int ntl = 0; ntl < 5; ++ntl)
                if (ntl < nlocal)
                    bc[ntl] = *reinterpret_cast<const bf16x8*>(
                        gw2f + (size_t)((w * 5 + ntl) * NS + s2) * 512 + lane8);
            {
                B8 af[4];
                #pragma unroll
                for (int mt = 0; mt < 4; ++mt) {
                    const ushort_t* p = &g1s[(mt * 16 + li) * G1S + 32 * (s + 1) + 8 * grp];
                    af[mt].d[0] = *reinterpret_cast<const uint2*>(p);
                    af[mt].d[1] = *reinterpret_cast<const uint2*>(p + 4);
                }
                #pragma unroll
                for (int ntl = 0; ntl < 5; ++ntl)
                    if (ntl < nlocal)
                        #pragma unroll
                        for (int mt = 0; mt < 4; ++mt)
                            acc[mt][ntl] = __builtin_amdgcn_mfma_f32_16x16x32_bf16(
                                af[mt].v, bn[ntl], acc[mt][ntl], 0, 0, 0);
            }
        }

        #pragma unroll
        for (int ntl = 0; ntl < 5; ++ntl) {
            if (ntl < nlocal) {
                int h = (w * 5 + ntl) * 16 + li;
                float bias = 0.f, fac = 0.f;
                if (h < H_) { bias = gb2[h]; fac = colw[j * H_ + h]; }
                #pragma unroll
                for (int mt = 0; mt < 4; ++mt)
                    #pragma unroll
                    for (int r = 0; r < 4; ++r)
                        partial[mt][r] += fmaxf(acc[mt][ntl][r] + bias, 0.f) * fac;
            }
        }
    }
    #pragma unroll
    for (int mt = 0; mt < 4; ++mt)
        #pragma unroll
        for (int r = 0; r < 4; ++r) {
            float v = partial[mt][r];
            v += __shfl_xor(v, 1);
            v += __shfl_xor(v, 2);
            v += __shfl_xor(v, 4);
            v += __shfl_xor(v, 8);
            if (li == 0) xpart[w][mt * 16 + 4 * grp + r] = v;
        }
    __syncthreads();

    if (tid < 64) {
        float v = colb[j];
        #pragma unroll
        for (int ww = 0; ww < 4; ++ww) v += xpart[ww][tid];
        xmean[(size_t)(b0 + tid) * D_ + j] = v;
    }
}

extern "C" void kernel_launch(void* const* d_in, const int* in_sizes, int n_in,
                              void* d_out, int out_size, void* d_ws, size_t ws_size,
                              hipStream_t stream) {
    const float* x     = (const float*)d_in[0];
    const float* eps   = (const float*)d_in[1];
    const float* Wm    = (const float*)d_in[2];
    const float* qz_w1 = (const float*)d_in[3];
    const float* qz_b1 = (const float*)d_in[4];
    const float* qz_w2 = (const float*)d_in[5];
    const float* qz_b2 = (const float*)d_in[6];
    const float* zm_w  = (const float*)d_in[7];
    const float* zm_b  = (const float*)d_in[8];
    const float* zl_w  = (const float*)d_in[9];
    const float* zl_b  = (const float*)d_in[10];
    const float* gw1   = (const float*)d_in[11];
    const float* gw2   = (const float*)d_in[12];
    const float* gb2   = (const float*)d_in[13];
    const float* colw  = (const float*)d_in[14];
    const float* colb  = (const float*)d_in[15];
    float* out = (float*)d_out;
    char* ws = (char*)d_ws;

    // workspace layout (bytes)
    ushort_t* gw1f = (ushort_t*)(ws + 0);          //  19,456 B
    ushort_t* gw2f = (ushort_t*)(ws + 19456);      // 194,560 B -> 214,016
    ushort_t* w1hi = (ushort_t*)(ws + 214016);     // 311,296 B -> 525,312
    ushort_t* w1lo = (ushort_t*)(ws + 525312);     // 311,296 B -> 836,608
    ushort_t* w2hi = (ushort_t*)(ws + 836608);     // 194,560 B -> 1,031,168
    ushort_t* w2lo = (ushort_t*)(ws + 1031168);    // 194,560 B -> 1,225,728
    ushort_t* w3hi = (ushort_t*)(ws + 1225728);    //  40,960 B -> 1,266,688
    ushort_t* w3lo = (ushort_t*)(ws + 1266688);    //  40,960 B -> 1,307,648
    float*    zb   = (float*)(ws + 1307648);       //  65,536 B -> 1,373,184

    prep_kernel<<<743, 64, 0, stream>>>(gw1, gw2, qz_w1, qz_w2, zm_w, zl_w,
                                        gw1f, gw2f, w1hi, w1lo, w2hi, w2lo, w3hi, w3lo);
    fused_encoder<<<32, 512, 0, stream>>>(x, w1hi, w1lo, w2hi, w2lo, w3hi, w3lo,
                                          qz_b1, qz_b2, zm_b, zl_b, eps, out, zb);
    decode_kernel<<<dim3(8, 512), 256, 0, stream>>>(zb, Wm, gw1f, gw2f, gb2, colw, colb, out);
}

// Round 14
// 112.050 us; speedup vs baseline: 1.6168x; 1.6168x over previous
//
#include <hip/hip_runtime.h>

#define B_ 512
#define D_ 512
#define L_ 32
#define H_ 300
#define NT 19       // 16-col n-tiles of H
#define NS 10       // 32-k steps over K=300 (zero-padded weights beyond 300)
#define G1S 308     // g1 LDS row stride (ushorts): <=2-way on stores+reads (measured 0)

typedef unsigned short ushort_t;
typedef __bf16 bf16x8 __attribute__((ext_vector_type(8)));
typedef float f32x4 __attribute__((ext_vector_type(4)));

union B8 { ushort_t u[8]; uint4 q; bf16x8 v; uint2 d[2]; __bf16 b[8]; };

__device__ __forceinline__ void split8(const float* fv, B8& hi, B8& lo) {
    #pragma unroll
    for (int i = 0; i < 8; ++i) {
        __bf16 h = (__bf16)fv[i];
        hi.b[i] = h;
        lo.b[i] = (__bf16)(fv[i] - (float)h);
    }
}

// ---------------- prep: swizzle weights into MFMA fragment layout ----------------
// frag elem i of lane l = B[k = 32*s + 8*(l>>4) + i][n = 16*nt + (l&15)]; OOR -> 0
// decoder weights: single bf16; encoder weights: hi/lo bf16 pair (split-fp32)
__global__ __launch_bounds__(64) void prep_kernel(
        const float* __restrict__ gw1, const float* __restrict__ gw2,
        const float* __restrict__ qw1, const float* __restrict__ qw2,
        const float* __restrict__ zmw, const float* __restrict__ zlw,
        ushort_t* __restrict__ gw1f, ushort_t* __restrict__ gw2f,
        ushort_t* __restrict__ w1hi, ushort_t* __restrict__ w1lo,
        ushort_t* __restrict__ w2hi, ushort_t* __restrict__ w2lo,
        ushort_t* __restrict__ w3hi, ushort_t* __restrict__ w3lo) {
    int blk = blockIdx.x;
    int l = threadIdx.x, grp = l >> 4, li = l & 15;
    if (blk < 209) {    // decoder weights, single bf16
        const float* src; int K, nt, s; ushort_t* dst;
        if (blk < 19) { nt = blk; s = 0; src = gw1; K = 32; dst = gw1f + (nt * 64 + l) * 8; }
        else { int i = blk - 19; nt = i / 10; s = i % 10; src = gw2; K = 300;
               dst = gw2f + ((nt * 10 + s) * 64 + l) * 8; }
        int n = nt * 16 + li;
        B8 V;
        #pragma unroll
        for (int i = 0; i < 8; ++i) {
            int k = 32 * s + 8 * grp + i;
            V.b[i] = (__bf16)((k < K && n < H_) ? src[k * H_ + n] : 0.f);
        }
        *reinterpret_cast<uint4*>(dst) = V.q;
    } else {            // encoder weights, hi/lo split
        const float* src = nullptr; int K, N, nt, s, stacked = 0;
        ushort_t *dh, *dl;
        if (blk < 513)      { int i = blk - 209; nt = i / 16; s = i % 16; src = qw1; K = 512; N = 300;
                              dh = w1hi + ((nt * 16 + s) * 64 + l) * 8; dl = w1lo + ((nt * 16 + s) * 64 + l) * 8; }
        else if (blk < 703) { int i = blk - 513; nt = i / 10; s = i % 10; src = qw2; K = 300; N = 300;
                              dh = w2hi + ((nt * 10 + s) * 64 + l) * 8; dl = w2lo + ((nt * 10 + s) * 64 + l) * 8; }
        else                { int i = blk - 703; nt = i / 10; s = i % 10; K = 300; N = 64; stacked = 1;
                              dh = w3hi + ((nt * 10 + s) * 64 + l) * 8; dl = w3lo + ((nt * 10 + s) * 64 + l) * 8; }
        int n = nt * 16 + li;
        float fv[8];
        #pragma unroll
        for (int i = 0; i < 8; ++i) {
            int k = 32 * s + 8 * grp + i;
            float v = 0.f;
            if (k < K && n < N) {
                if (!stacked) v = src[k * N + n];
                else          v = (n < 32) ? zmw[k * 32 + n] : zlw[k * 32 + (n - 32)];
            }
            fv[i] = v;
        }
        B8 Vh, Vl;
        split8(fv, Vh, Vl);
        *reinterpret_cast<uint4*>(dh) = Vh.q;
        *reinterpret_cast<uint4*>(dl) = Vl.q;
    }
}

// ------------- encoder GEMM, split-bf16 (~fp32 accuracy): out = act(A @ W + bias) -------
// grid (M/16, ceil(N/64)); block = 16 rows, wave w owns n-tile blockIdx.y*4 + w
template<int KSTEPS, bool RELU>
__global__ __launch_bounds__(256) void enc_gemm_f32(const float* __restrict__ A, int lda,
        const ushort_t* __restrict__ Whi, const ushort_t* __restrict__ Wlo,
        const float* __restrict__ bias, float* __restrict__ out, int ldo,
        int Ncols, int ntiles) {
    const int tid = threadIdx.x;
    const int w = tid >> 6, lane = tid & 63;
    const int grp = lane >> 4, li = lane & 15;
    const int r0 = blockIdx.x * 16;
    const int nt = blockIdx.y * 4 + w;
    const bool active = nt < ntiles;

    f32x4 acc = {0.f, 0.f, 0.f, 0.f};
    for (int s = 0; s < KSTEPS; ++s) {
        int kb = 32 * s + 8 * grp;
        B8 Ah, Al;
        if (kb + 8 <= lda) {
            const float* ap = A + (size_t)(r0 + li) * lda + kb;
            float4 f0 = *reinterpret_cast<const float4*>(ap);
            float4 f1 = *reinterpret_cast<const float4*>(ap + 4);
            float fv[8] = {f0.x, f0.y, f0.z, f0.w, f1.x, f1.y, f1.z, f1.w};
            split8(fv, Ah, Al);
        } else {
            Ah.q = make_uint4(0, 0, 0, 0);
            Al.q = make_uint4(0, 0, 0, 0);
        }
        if (active) {
            bf16x8 bh = *reinterpret_cast<const bf16x8*>(
                Whi + ((size_t)(nt * KSTEPS + s) * 64 + lane) * 8);
            bf16x8 bl = *reinterpret_cast<const bf16x8*>(
                Wlo + ((size_t)(nt * KSTEPS + s) * 64 + lane) * 8);
            acc = __builtin_amdgcn_mfma_f32_16x16x32_bf16(Ah.v, bh, acc, 0, 0, 0);
            acc = __builtin_amdgcn_mfma_f32_16x16x32_bf16(Al.v, bh, acc, 0, 0, 0);
            acc = __builtin_amdgcn_mfma_f32_16x16x32_bf16(Ah.v, bl, acc, 0, 0, 0);
        }
    }
    if (active) {
        int h = nt * 16 + li;
        float bv = (bias != nullptr && h < Ncols) ? bias[h] : 0.f;
        #pragma unroll
        for (int r = 0; r < 4; ++r) {
            float v = acc[r] + bv;
            if (RELU) v = fmaxf(v, 0.f);
            if (h >= Ncols) v = 0.f;
            out[(size_t)(r0 + 4 * grp + r) * ldo + h] = v;
        }
    }
}

// -------- latent head (split-bf16) + reparameterize, fused: zm|zl = h2 @ w3; z = ... -----
__global__ __launch_bounds__(256) void enc3_reparam(const float* __restrict__ h2,
        const ushort_t* __restrict__ w3hi, const ushort_t* __restrict__ w3lo,
        const float* __restrict__ zmb, const float* __restrict__ zlb,
        const float* __restrict__ eps, float* __restrict__ out, float* __restrict__ zb) {
    __shared__ float zs[16][64];
    const int tid = threadIdx.x;
    const int w = tid >> 6, lane = tid & 63;
    const int grp = lane >> 4, li = lane & 15;
    const int r0 = blockIdx.x * 16;

    f32x4 acc = {0.f, 0.f, 0.f, 0.f};
    for (int s = 0; s < 10; ++s) {
        int kb = 32 * s + 8 * grp;
        B8 Ah, Al;
        if (kb + 8 <= 304) {
            const float* ap = h2 + (size_t)(r0 + li) * 304 + kb;
            float4 f0 = *reinterpret_cast<const float4*>(ap);
            float4 f1 = *reinterpret_cast<const float4*>(ap + 4);
            float fv[8] = {f0.x, f0.y, f0.z, f0.w, f1.x, f1.y, f1.z, f1.w};
            split8(fv, Ah, Al);
        } else {
            Ah.q = make_uint4(0, 0, 0, 0);
            Al.q = make_uint4(0, 0, 0, 0);
        }
        bf16x8 bh = *reinterpret_cast<const bf16x8*>(w3hi + ((size_t)(w * 10 + s) * 64 + lane) * 8);
        bf16x8 bl = *reinterpret_cast<const bf16x8*>(w3lo + ((size_t)(w * 10 + s) * 64 + lane) * 8);
        acc = __builtin_amdgcn_mfma_f32_16x16x32_bf16(Ah.v, bh, acc, 0, 0, 0);
        acc = __builtin_amdgcn_mfma_f32_16x16x32_bf16(Al.v, bh, acc, 0, 0, 0);
        acc = __builtin_amdgcn_mfma_f32_16x16x32_bf16(Ah.v, bl, acc, 0, 0, 0);
    }
    #pragma unroll
    for (int r = 0; r < 4; ++r) zs[4 * grp + r][w * 16 + li] = acc[r];
    __syncthreads();

    for (int idx = tid; idx < 512; idx += 256) {
        int m = idx >> 5, l2 = idx & 31;
        int row = r0 + m;
        float zm = zs[m][l2] + zmb[l2];
        float zl = zs[m][32 + l2] + zlb[l2];
        float zv = zm + eps[row * 32 + l2] * expf(0.5f * zl);
        out[B_ * D_ + row * 32 + l2] = zv;
        out[B_ * D_ + B_ * L_ + row * 32 + l2] = zm;
        out[B_ * D_ + 2 * B_ * L_ + row * 32 + l2] = zl;
        zb[row * 32 + l2] = zv;
    }
}

// ---------------- decoder: one block = (column j, 64 batch rows), 4 waves ----------------
// wave w owns n-tiles w*5..w*5+4 (w=3: 4) and ALL 4 m-tiles: 20 MFMA per af-set
__global__ __launch_bounds__(256, 3) void decode_kernel(
        const float* __restrict__ z, const float* __restrict__ Wmask,
        const ushort_t* __restrict__ gw1f, const ushort_t* __restrict__ gw2f,
        const float* __restrict__ gb2, const float* __restrict__ colw,
        const float* __restrict__ colb, float* __restrict__ xmean) {
    __shared__ __align__(16) ushort_t g1s[64 * G1S + 16];    // 39,456 B
    __shared__ float xpart[4][64];                           //  1,024 B

    const int j    = blockIdx.y;
    const int b0   = blockIdx.x * 64;
    const int tid  = threadIdx.x;
    const int w    = tid >> 6;
    const int lane = tid & 63;
    const int grp  = lane >> 4, li = lane & 15;
    const int nlocal = (w == 3) ? 4 : 5;          // n-tiles 19 = 5+5+5+4 across waves

    // phase 0: masked B-frags in registers (all 4 m-tiles, per wave); zero pads
    B8 bm[4];
    {
        const float* wp = Wmask + (size_t)j * L_ + 8 * grp;
        float4 w0 = *reinterpret_cast<const float4*>(wp);
        float4 w1 = *reinterpret_cast<const float4*>(wp + 4);
        float wv[8] = {w0.x, w0.y, w0.z, w0.w, w1.x, w1.y, w1.z, w1.w};
        #pragma unroll
        for (int mt = 0; mt < 4; ++mt) {
            const float* zp = z + (size_t)(b0 + mt * 16 + li) * L_ + 8 * grp;
            float4 z0 = *reinterpret_cast<const float4*>(zp);
            float4 z1 = *reinterpret_cast<const float4*>(zp + 4);
            float zv[8] = {z0.x, z0.y, z0.z, z0.w, z1.x, z1.y, z1.z, z1.w};
            #pragma unroll
            for (int i = 0; i < 8; ++i) bm[mt].b[i] = (__bf16)(wv[i] * zv[i]);
        }
        // zero pad cols 304..307 (never written by phase 1) + 16-elem tail:
        // phase-2 s=9 reads cols up to 319 -> spill into next row (finite g1) or tail,
        // multiplied by zero-padded (k>=300) gw2f B entries
        for (int idx = tid; idx < 272; idx += 256) {
            if (idx < 256) g1s[(idx >> 2) * G1S + 304 + (idx & 3)] = 0;
            else           g1s[64 * G1S + (idx - 256)] = 0;
        }
    }
    __syncthreads();

    // phase 1 (swapped): D = gw1^T(A) x masked^T(B) -> lane holds g1[b=li][4 consec h]
    #pragma unroll
    for (int ntl = 0; ntl < 5; ++ntl) {
        if (ntl < nlocal) {
            int nt = w * 5 + ntl;
            bf16x8 ga = *reinterpret_cast<const bf16x8*>(gw1f + (nt * 64 + lane) * 8);
            #pragma unroll
            for (int mt = 0; mt < 4; ++mt) {
                f32x4 c = {0.f, 0.f, 0.f, 0.f};
                c = __builtin_amdgcn_mfma_f32_16x16x32_bf16(ga, bm[mt].v, c, 0, 0, 0);
                // c[r] = g1[b = mt*16+li][h = nt*16 + 4*grp + r]
                B8 P;
                #pragma unroll
                for (int r = 0; r < 4; ++r) P.b[r] = (__bf16)fmaxf(c[r], 0.f);
                *reinterpret_cast<uint2*>(&g1s[(mt * 16 + li) * G1S + nt * 16 + 4 * grp]) = P.d[0];
            }
        }
    }
    __syncthreads();

    // phase 2: g2 = relu(g1 @ gw2 + gb2); af reused across 5 n-tiles (20 MFMA/af-set)
    {
        f32x4 acc[4][5];
        #pragma unroll
        for (int mt = 0; mt < 4; ++mt)
            #pragma unroll
            for (int n = 0; n < 5; ++n) acc[mt][n] = {0.f, 0.f, 0.f, 0.f};

        const size_t lane8 = (size_t)lane * 8;
        for (int s = 0; s < NS; ++s) {
            B8 af[4];
            #pragma unroll
            for (int mt = 0; mt < 4; ++mt) {
                const ushort_t* p = &g1s[(mt * 16 + li) * G1S + 32 * s + 8 * grp];
                af[mt].d[0] = *reinterpret_cast<const uint2*>(p);
                af[mt].d[1] = *reinterpret_cast<const uint2*>(p + 4);
            }
            #pragma unroll
            for (int ntl = 0; ntl < 5; ++ntl) {
                if (ntl < nlocal) {
                    bf16x8 bfr = *reinterpret_cast<const bf16x8*>(
                        gw2f + (size_t)((w * 5 + ntl) * NS + s) * 512 + lane8);
                    #pragma unroll
                    for (int mt = 0; mt < 4; ++mt)
                        acc[mt][ntl] = __builtin_amdgcn_mfma_f32_16x16x32_bf16(
                            af[mt].v, bfr, acc[mt][ntl], 0, 0, 0);
                }
            }
        }

        // epilogue: relu(acc + gb2) * colw[j], reduce over h (li lanes), no atomics
        float partial[4][4] = {};
        #pragma unroll
        for (int ntl = 0; ntl < 5; ++ntl) {
            if (ntl < nlocal) {
                int h = (w * 5 + ntl) * 16 + li;
                float bias = 0.f, fac = 0.f;
                if (h < H_) { bias = gb2[h]; fac = colw[j * H_ + h]; }
                #pragma unroll
                for (int mt = 0; mt < 4; ++mt)
                    #pragma unroll
                    for (int r = 0; r < 4; ++r)
                        partial[mt][r] += fmaxf(acc[mt][ntl][r] + bias, 0.f) * fac;
            }
        }
        #pragma unroll
        for (int mt = 0; mt < 4; ++mt)
            #pragma unroll
            for (int r = 0; r < 4; ++r) {
                float v = partial[mt][r];
                v += __shfl_xor(v, 1);
                v += __shfl_xor(v, 2);
                v += __shfl_xor(v, 4);
                v += __shfl_xor(v, 8);
                if (li == 0) xpart[w][mt * 16 + 4 * grp + r] = v;
            }
    }
    __syncthreads();

    if (tid < 64) {
        float v = colb[j];
        #pragma unroll
        for (int ww = 0; ww < 4; ++ww) v += xpart[ww][tid];
        xmean[(size_t)(b0 + tid) * D_ + j] = v;
    }
}

extern "C" void kernel_launch(void* const* d_in, const int* in_sizes, int n_in,
                              void* d_out, int out_size, void* d_ws, size_t ws_size,
                              hipStream_t stream) {
    const float* x     = (const float*)d_in[0];
    const float* eps   = (const float*)d_in[1];
    const float* Wm    = (const float*)d_in[2];
    const float* qz_w1 = (const float*)d_in[3];
    const float* qz_b1 = (const float*)d_in[4];
    const float* qz_w2 = (const float*)d_in[5];
    const float* qz_b2 = (const float*)d_in[6];
    const float* zm_w  = (const float*)d_in[7];
    const float* zm_b  = (const float*)d_in[8];
    const float* zl_w  = (const float*)d_in[9];
    const float* zl_b  = (const float*)d_in[10];
    const float* gw1   = (const float*)d_in[11];
    const float* gw2   = (const float*)d_in[12];
    const float* gb2   = (const float*)d_in[13];
    const float* colw  = (const float*)d_in[14];
    const float* colb  = (const float*)d_in[15];
    float* out = (float*)d_out;
    char* ws = (char*)d_ws;

    // workspace layout (bytes)
    ushort_t* gw1f = (ushort_t*)(ws + 0);          //  19,456 B
    ushort_t* gw2f = (ushort_t*)(ws + 19456);      // 194,560 B -> 214,016
    ushort_t* w1hi = (ushort_t*)(ws + 214016);     // 311,296 B -> 525,312
    ushort_t* w1lo = (ushort_t*)(ws + 525312);     // 311,296 B -> 836,608
    ushort_t* w2hi = (ushort_t*)(ws + 836608);     // 194,560 B -> 1,031,168
    ushort_t* w2lo = (ushort_t*)(ws + 1031168);    // 194,560 B -> 1,225,728
    ushort_t* w3hi = (ushort_t*)(ws + 1225728);    //  40,960 B -> 1,266,688
    ushort_t* w3lo = (ushort_t*)(ws + 1266688);    //  40,960 B -> 1,307,648
    float*    h1   = (float*)(ws + 1307648);       // 622,592 B -> 1,930,240  [512][304] f32
    float*    h2   = (float*)(ws + 214016);        // 622,592 B (overlaps dead w1hi/w1lo)
    float*    zb   = (float*)(ws + 1930240);       //  65,536 B -> 1,995,776  [512][32] f32

    prep_kernel<<<743, 64, 0, stream>>>(gw1, gw2, qz_w1, qz_w2, zm_w, zl_w,
                                        gw1f, gw2f, w1hi, w1lo, w2hi, w2lo, w3hi, w3lo);
    enc_gemm_f32<16, true><<<dim3(32, 5), 256, 0, stream>>>(
        x, 512, w1hi, w1lo, qz_b1, h1, 304, 300, NT);
    enc_gemm_f32<10, true><<<dim3(32, 5), 256, 0, stream>>>(
        h1, 304, w2hi, w2lo, qz_b2, h2, 304, 300, NT);
    enc3_reparam<<<32, 256, 0, stream>>>(h2, w3hi, w3lo, zm_b, zl_b, eps, out, zb);
    decode_kernel<<<dim3(8, 512), 256, 0, stream>>>(zb, Wm, gw1f, gw2f, gb2, colw, colb, out);
}